// Round 9
// baseline (26340.213 us; speedup 1.0000x reference)
//
#include <hip/hip_runtime.h>
#include <math.h>

// DARTS recurrent cell on MI355X — persistent cooperative kernel, v9.
// v8 -> v9: weight stream moved to a global_load_lds DMA ring (compiler cannot
// sink it; zero data VGPRs). LDS = 16KB arena + 2x64KB ring. 20 blocks/step;
// wave w DMAs/consumes only its own 8KB sub-region (ks 4w..4w+3) -> ring is
// wave-private; consume(b) -> lgkmcnt(0) -> DMA(b+2). Every block has a
// __syncthreads (per-wave vmcnt(0)) between issue and consume = landing fence.
// Sync semantics (flags, one acquire/step) identical to v6-v8 (proven).

typedef __attribute__((ext_vector_type(8))) _Float16 half8;
typedef __attribute__((ext_vector_type(4))) float f32x4;
typedef __attribute__((ext_vector_type(8))) unsigned short us8;

#define NH 1024
#define SCALE 2048.f
#define INVS  (1.f/2048.f)
#define WF_BYTES 83886080ull
#define FA_BYTES 1572864ull
#define T_STEPS  256

#define LGKM0() asm volatile("s_waitcnt lgkmcnt(0)" ::: "memory")
#define LBAR()  asm volatile("s_waitcnt lgkmcnt(0)\n\ts_barrier" ::: "memory")

typedef const __attribute__((address_space(1))) void* gas_ptr;
typedef __attribute__((address_space(3))) void* las_ptr;

__device__ __forceinline__ float sigf(float x){ return 1.f/(1.f+__expf(-x)); }
__device__ __forceinline__ void limbs2(float x, _Float16& a, _Float16& b){
    a = (_Float16)x; b = (_Float16)((x - (float)a)*SCALE);
}

// ---------------- weight pre-swizzle (identical to v4-v8, proven) ------------
struct Pre { const float* W0; const float* Ws; unsigned short* wf; };

__global__ __launch_bounds__(256) void preconv(Pre d) {
    int gid  = blockIdx.x * 4 + (threadIdx.x >> 6);
    int lane = threadIdx.x & 63;
    const float* W; unsigned short* dst; int nks, cg, ks;
    if (gid < 8192) {
        W = d.W0; dst = d.wf; nks = 64; cg = gid >> 6; ks = gid & 63;
    } else {
        int g = gid - 8192; int mm = g >> 12; int wi = g & 4095;
        W   = d.Ws + (size_t)mm * (1024 * 2048);
        dst = d.wf + 8388608ull + (size_t)mm * 4194304ull;
        nks = 32; cg = wi >> 5; ks = wi & 31;
    }
    int c  = cg * 16 + (lane & 15);
    int kb = ks * 32 + (lane >> 4) * 8;
    half8 h0, h1;
    #pragma unroll
    for (int j = 0; j < 8; ++j) {
        _Float16 p, q; limbs2(W[(size_t)(kb + j) * 2048 + c], p, q);
        h0[j] = p; h1[j] = q;
    }
    unsigned short* o = dst + ((size_t)cg * nks + ks) * 1024 + lane * 8;
    *(half8*)o         = h0;
    *(half8*)(o + 512) = h1;
}

// -------- init: hidden -> interleaved H frag plane; flag init ----------------
__global__ __launch_bounds__(256) void initk(const float* hidden, char* fa, unsigned* flags) {
    int gid = blockIdx.x * 256 + threadIdx.x;
    if (gid < 1536) flags[gid] = (gid < 256) ? 1u : 0u;
    #pragma unroll
    for (int e = 0; e < 4; ++e) {
        int i = gid * 4 + e;
        int row = i >> 10, col = i & 1023;
        int rt = row >> 4, rowf = row & 15;
        int ksp = col >> 5, kin = col & 31;
        int lanep = (kin >> 3) * 16 + rowf;
        size_t off = (size_t)rt * 65536 + ((size_t)ksp * 64 + lanep) * 32 + (kin & 7) * 4;
        _Float16 u0, u1; limbs2(hidden[i], u0, u1);
        unsigned pk = (unsigned)__builtin_bit_cast(unsigned short, u0) |
                      ((unsigned)__builtin_bit_cast(unsigned short, u1) << 16);
        *(unsigned*)(fa + off) = pk;
    }
}

// ------------------------------ device helpers -------------------------------
__device__ __forceinline__ void aload(const char* fa, int ks, int lane, half8& a0, half8& a1) {
    const char* p = fa + ((size_t)ks * 64 + lane) * 32;
    us8 q0 = *(const us8*)p;
    us8 q1 = *(const us8*)(p + 16);
    a0 = __builtin_bit_cast(half8, __builtin_shufflevector(q0, q1, 0,2,4,6,8,10,12,14));
    a1 = __builtin_bit_cast(half8, __builtin_shufflevector(q0, q1, 1,3,5,7,9,11,13,15));
}
__device__ __forceinline__ void mfma6(half8 a0, half8 a1, half8 w0, half8 w1,
                                      f32x4& x0, f32x4& x1) {
    x0 = __builtin_amdgcn_mfma_f32_16x16x32_f16(a0, w0, x0, 0, 0, 0);
    x1 = __builtin_amdgcn_mfma_f32_16x16x32_f16(a0, w1, x1, 0, 0, 0);
    x1 = __builtin_amdgcn_mfma_f32_16x16x32_f16(a1, w0, x1, 0, 0, 0);
}
__device__ __forceinline__ void rwrite1(float* arena, int wave, int lane,
        f32x4 c0, f32x4 c1, f32x4 h0, f32x4 h1) {
    float* b = arena + wave * 512;
    #pragma unroll
    for (int r = 0; r < 4; ++r) {
        b[lane * 4 + r]       = c0[r] + c1[r] * INVS;
        b[256 + lane * 4 + r] = h0[r] + h1[r] * INVS;
    }
}
__device__ __forceinline__ void rsum1(const float* arena, int idx, float& cs, float& hs) {
    float c = 0.f, h = 0.f;
    #pragma unroll
    for (int w = 0; w < 8; ++w) {
        c += arena[w * 512 + idx];
        h += arena[w * 512 + 256 + idx];
    }
    cs = c; hs = h;
}
__device__ __forceinline__ void fstore(char* fa, int offp, float v) {
    _Float16 u0, u1; limbs2(v, u0, u1);
    unsigned pk = (unsigned)__builtin_bit_cast(unsigned short, u0) |
                  ((unsigned)__builtin_bit_cast(unsigned short, u1) << 16);
    __hip_atomic_store((unsigned*)(fa + offp), pk, __ATOMIC_RELAXED, __HIP_MEMORY_SCOPE_AGENT);
}
template<int ACQ>
__device__ __forceinline__ void pollw(unsigned* f, unsigned tgt, int lane) {
    unsigned v = __hip_atomic_load(f + lane, __ATOMIC_RELAXED, __HIP_MEMORY_SCOPE_AGENT);
    while (__ballot(v < tgt)) {
        __builtin_amdgcn_s_sleep(2);
        v = __hip_atomic_load(f + lane, __ATOMIC_RELAXED, __HIP_MEMORY_SCOPE_AGENT);
    }
    if (ACQ)
        (void)__hip_atomic_load(f, __ATOMIC_ACQUIRE, __HIP_MEMORY_SCOPE_AGENT);
}
__device__ __forceinline__ void publish(unsigned* slot, unsigned v) {
    __hip_atomic_store(slot, v, __ATOMIC_RELAXED, __HIP_MEMORY_SCOPE_AGENT);
}

// ------------------------------ persistent kernel ----------------------------
struct PK {
    const float* x; const float* hidden;
    const unsigned short* wf;
    char* fa; unsigned* flags; float* out;
};

__global__ __launch_bounds__(512, 2) void persist(PK p) {
    __shared__ char ring[2][65536];          // 128 KB weight DMA ring
    __shared__ float arena[4096];            // 16 KB reduce arena

    const int tid = threadIdx.x;
    const int wave = tid >> 6, lane = tid & 63;
    const int l15 = lane & 15, lg = lane >> 4;
    const int lg8 = lg * 8;
    const int bx = blockIdx.x;
    const int cg = (bx & 7) * 8 + ((bx >> 3) & 7);
    const int rt = bx >> 6;

    const unsigned short* wf0 = p.wf;
    // 20 weight blocks/step, each 64KB contiguous (32 ks x 2KB frag-pairs):
    // 0:XC 1:XH 2:HC 3:HH | then (C,H) for Ws0,Ws1,Ws2,Ws3,Ws4,Ws6,Ws5,Ws7
    const unsigned short* gB[20];
    {
        gB[0] = wf0 + (size_t)(cg * 64) * 1024;
        gB[1] = wf0 + (size_t)((cg + 64) * 64) * 1024;
        gB[2] = wf0 + (size_t)(cg * 64 + 32) * 1024;
        gB[3] = wf0 + (size_t)((cg + 64) * 64 + 32) * 1024;
        const int mo[8] = {0, 1, 2, 3, 4, 6, 5, 7};
        #pragma unroll
        for (int u = 0; u < 8; ++u) {
            const unsigned short* wm = p.wf + 8388608ull + (size_t)mo[u] * 4194304ull;
            gB[4 + 2 * u]     = wm + (size_t)cg * 32768;
            gB[4 + 2 * u + 1] = wm + (size_t)(cg + 64) * 32768;
        }
    }

    char* FAH  = p.fa + (size_t)(0 * 4 + rt) * 65536;
    char* FAS0 = p.fa + (size_t)(1 * 4 + rt) * 65536;
    char* FAS1 = p.fa + (size_t)(2 * 4 + rt) * 65536;
    char* FAS2 = p.fa + (size_t)(3 * 4 + rt) * 65536;
    char* FAS3 = p.fa + (size_t)(4 * 4 + rt) * 65536;
    char* FAS5 = p.fa + (size_t)(5 * 4 + rt) * 65536;
    #define FLG(tn) (p.flags + ((tn) * 4 + rt) * 64)

    // DMA block b into its slot: 8 x global_load_lds(16B/lane), wave-private 8KB
    #define DMA(b) do { \
        const char* _g = (const char*)gB[b] + wave * 8192 + lane * 16; \
        char* _l = &ring[(b) & 1][wave * 8192]; \
        _Pragma("unroll") \
        for (int _i = 0; _i < 8; ++_i) \
            __builtin_amdgcn_global_load_lds((gas_ptr)(_g + _i * 1024), \
                                             (las_ptr)(_l + _i * 1024), 16, 0, 0); \
    } while (0)
    // consume block b (wave's 4 ks) with A-frag arrays into 2 accumulators
    #define CONS(b, A0, A1, X0, X1) do { \
        _Pragma("unroll") \
        for (int _i = 0; _i < 4; ++_i) { \
            const char* _p = &ring[(b) & 1][(wave * 4 + _i) * 2048 + lane * 16]; \
            half8 _w0 = *(const half8*)_p; \
            half8 _w1 = *(const half8*)(_p + 1024); \
            mfma6(A0[_i], A1[_i], _w0, _w1, X0, X1); \
        } \
    } while (0)
    #define ALD(dst0, dst1, fa) do { \
        _Pragma("unroll") \
        for (int _i = 0; _i < 4; ++_i) aload(fa, wave * 4 + _i, lane, dst0[_i], dst1[_i]); \
    } while (0)

    const int rowf = tid >> 4, colf = tid & 15;
    const size_t opos = (size_t)(rt * 16 + rowf) * NH + cg * 16 + colf;
    const int idx = colf * 4 + (rowf >> 2) * 64 + (rowf & 3);
    int offp;
    {
        int col = cg * 16 + colf;
        int ksp = col >> 5, kin = col & 31;
        int lanep = (kin >> 3) * 16 + rowf;
        offp = (ksp * 64 + lanep) * 32 + (kin & 7) * 4;
    }
    float hprev = 0.f, s0v = 0.f, s1v = 0.f, s2v = 0.f, s3v = 0.f, s5v = 0.f, runsum = 0.f;
    if (tid < 256) hprev = p.hidden[opos];
    const int xrow = rt * 16 + l15;

    // prologue: prime blocks 0,1 (XC, XH); drained by the sync below
    DMA(0); DMA(1);
    __syncthreads();

    for (int t = 0; t < T_STEPS; ++t) {
        const float* xt = p.x + (size_t)t * 65536;
        half8 a0[4], a1[4];

        // ===== E0 / L1: x-part pre-poll, h-part post-poll ====================
        f32x4 c0 = {}, c1 = {}, h0 = {}, h1 = {};
        {
            half8 xa0[4], xa1[4];
            #pragma unroll
            for (int i = 0; i < 4; ++i) {
                const int ks = wave * 4 + i;
                const float* xp = xt + (size_t)xrow * NH + ks * 32 + lg8;
                float4 v0 = *(const float4*)xp, v1 = *(const float4*)(xp + 4);
                float fv[8] = {v0.x, v0.y, v0.z, v0.w, v1.x, v1.y, v1.z, v1.w};
                #pragma unroll
                for (int j = 0; j < 8; ++j) { _Float16 u, w2; limbs2(fv[j], u, w2); xa0[i][j] = u; xa1[i][j] = w2; }
            }
            CONS(0, xa0, xa1, c0, c1); LGKM0(); DMA(2);
            CONS(1, xa0, xa1, h0, h1); LGKM0(); DMA(3);
        }
        if (wave == 7) pollw<1>(FLG(0), t + 1, lane);   // the step's ONE acquire
        __syncthreads();                                 // drains b2,b3; orders acquire
        {
            half8 ha0[4], ha1[4];
            ALD(ha0, ha1, FAH);
            CONS(2, ha0, ha1, c0, c1); LGKM0(); DMA(4);
            CONS(3, ha0, ha1, h0, h1); LGKM0(); DMA(5);
            rwrite1(arena, wave, lane, c0, c1, h0, h1);
        }
        LBAR();
        if (tid < 256) {
            float cs, hs; rsum1(arena, idx, cs, hs);
            s0v = hprev + sigf(cs) * (tanhf(hs) - hprev);
            fstore(FAS0, offp, s0v);
        }
        __syncthreads();
        if (tid == 0) publish(FLG(1) + cg, t + 1);

        // ===== E1 / L2: s1 = comb(s0, s0 @ Ws0) ==============================
        if (wave == 7) pollw<0>(FLG(1), t + 1, lane);
        __syncthreads();                                 // drains b4,b5
        ALD(a0, a1, FAS0);
        {
            f32x4 X0 = {}, X1 = {}, Y0 = {}, Y1 = {};
            CONS(4, a0, a1, X0, X1); LGKM0(); DMA(6);
            CONS(5, a0, a1, Y0, Y1); LGKM0(); DMA(7);
            rwrite1(arena, wave, lane, X0, X1, Y0, Y1);
        }
        LBAR();
        if (tid < 256) {
            float cs, hs; rsum1(arena, idx, cs, hs);
            s1v = s0v + sigf(cs) * (sigf(hs) - s0v);
            fstore(FAS1, offp, s1v);
            runsum = s1v;
        }
        __syncthreads();
        if (tid == 0) publish(FLG(2) + cg, t + 1);

        // ===== E2 / L3: s2,s3,s4 from s1 =====================================
        if (wave == 7) pollw<0>(FLG(2), t + 1, lane);
        __syncthreads();                                 // drains b6,b7
        ALD(a0, a1, FAS1);
        {
            f32x4 X0 = {}, X1 = {}, Y0 = {}, Y1 = {};
            CONS(6, a0, a1, X0, X1); LGKM0(); DMA(8);
            CONS(7, a0, a1, Y0, Y1); LGKM0(); DMA(9);
            rwrite1(arena, wave, lane, X0, X1, Y0, Y1);
        }
        LBAR();
        if (tid < 256) {
            float cs, hs; rsum1(arena, idx, cs, hs);
            s2v = s1v + sigf(cs) * (fmaxf(hs, 0.f) - s1v);
            fstore(FAS2, offp, s2v);
        }
        __syncthreads();
        if (tid == 0) publish(FLG(3) + cg, t + 1);
        {
            f32x4 X0 = {}, X1 = {}, Y0 = {}, Y1 = {};
            CONS(8, a0, a1, X0, X1); LGKM0(); DMA(10);
            CONS(9, a0, a1, Y0, Y1); LGKM0(); DMA(11);
            rwrite1(arena, wave, lane, X0, X1, Y0, Y1);
        }
        LBAR();
        if (tid < 256) {
            float cs, hs; rsum1(arena, idx, cs, hs);
            s3v = s1v + sigf(cs) * (fmaxf(hs, 0.f) - s1v);
            fstore(FAS3, offp, s3v);
        }
        __syncthreads();
        if (tid == 0) publish(FLG(4) + cg, t + 1);
        {
            f32x4 X0 = {}, X1 = {}, Y0 = {}, Y1 = {};
            CONS(10, a0, a1, X0, X1); LGKM0(); DMA(12);
            CONS(11, a0, a1, Y0, Y1); LGKM0(); DMA(13);
            rwrite1(arena, wave, lane, X0, X1, Y0, Y1);
        }
        LBAR();
        if (tid < 256) {
            float cs, hs; rsum1(arena, idx, cs, hs);
            float s4v = s1v + sigf(cs) * (hs - s1v);
            runsum += s2v + s3v + s4v;
        }
        // no barrier: E3's post-poll sync orders arena reuse & drains b12,b13

        // ===== E3 / L4: s5 = comb(s2,Ws4), s7 = comb(s3,Ws6) =================
        if (wave == 7) { pollw<0>(FLG(3), t + 1, lane); pollw<0>(FLG(4), t + 1, lane); }
        __syncthreads();                                 // drains b12,b13
        {
            half8 bb0[4], bb1[4];
            ALD(a0, a1, FAS2);
            ALD(bb0, bb1, FAS3);
            f32x4 X0 = {}, X1 = {}, Y0 = {}, Y1 = {};
            CONS(12, a0, a1, X0, X1); LGKM0(); DMA(14);
            CONS(13, a0, a1, Y0, Y1); LGKM0(); DMA(15);
            rwrite1(arena, wave, lane, X0, X1, Y0, Y1);
            LBAR();
            if (tid < 256) {
                float cs, hs; rsum1(arena, idx, cs, hs);
                s5v = s2v + sigf(cs) * (tanhf(hs) - s2v);
                fstore(FAS5, offp, s5v);
            }
            __syncthreads();
            if (tid == 0) publish(FLG(5) + cg, t + 1);
            f32x4 U0 = {}, U1 = {}, V0 = {}, V1 = {};
            CONS(14, bb0, bb1, U0, U1); LGKM0(); DMA(16);
            CONS(15, bb0, bb1, V0, V1); LGKM0(); DMA(17);
            rwrite1(arena, wave, lane, U0, U1, V0, V1);
            LBAR();
            if (tid < 256) {
                float cs, hs; rsum1(arena, idx, cs, hs);
                float s7v = s3v + sigf(cs) * (tanhf(hs) - s3v);
                runsum += s5v + s7v;
            }
            // no barrier: E4's post-poll sync orders arena reuse & drains b16,b17
        }

        // ===== E4 / L5: s6,s8 from s5 + mean -> out[t] =======================
        if (wave == 7) pollw<0>(FLG(5), t + 1, lane);
        __syncthreads();                                 // drains b16,b17
        {
            ALD(a0, a1, FAS5);
            f32x4 X0 = {}, X1 = {}, Y0 = {}, Y1 = {};
            CONS(16, a0, a1, X0, X1); LGKM0(); DMA(18);
            CONS(17, a0, a1, Y0, Y1); LGKM0(); DMA(19);
            rwrite1(arena, wave, lane, X0, X1, Y0, Y1);
            __syncthreads();                             // drains b18,b19 (consumed below)
            float c6 = 0.f, h6 = 0.f;
            if (tid < 256) rsum1(arena, idx, c6, h6);
            LBAR();                                      // readers done before rewrite
            f32x4 U0 = {}, U1 = {}, V0 = {}, V1 = {};
            CONS(18, a0, a1, U0, U1); LGKM0(); DMA(0);   // prime next step's XC
            CONS(19, a0, a1, V0, V1); LGKM0(); DMA(1);   // prime next step's XH
            rwrite1(arena, wave, lane, U0, U1, V0, V1);
            LBAR();
            if (tid < 256) {
                float c8, h8; rsum1(arena, idx, c8, h8);
                float s6 = s5v + sigf(c6) * (sigf(h6) - s5v);
                float s8 = s5v + sigf(c8) * (fmaxf(h8, 0.f) - s5v);
                float v = 0.125f * (runsum + s6 + s8);
                p.out[(size_t)t * 65536 + opos] = v;
                fstore(FAH, offp, v);
                hprev = v;
            }
            __syncthreads();                             // drains b0,b1 + fstores
            if (tid == 0) publish(FLG(0) + cg, t + 2);
        }
    }
    #undef FLG
    #undef DMA
    #undef CONS
    #undef ALD
}

// ---------------------------------- host -------------------------------------
extern "C" void kernel_launch(void* const* d_in, const int* in_sizes, int n_in,
                              void* d_out, int out_size, void* d_ws, size_t ws_size,
                              hipStream_t stream) {
    (void)in_sizes; (void)n_in; (void)out_size; (void)ws_size;
    const float* inputs = (const float*)d_in[0];
    const float* hidden = (const float*)d_in[1];
    const float* W0     = (const float*)d_in[2];
    const float* Ws     = (const float*)d_in[3];
    float* out = (float*)d_out;

    char* base = (char*)d_ws;
    unsigned short* wf = (unsigned short*)base;
    char* fa = base + WF_BYTES;
    unsigned* flags = (unsigned*)(fa + FA_BYTES);

    initk<<<64, 256, 0, stream>>>(hidden, fa, flags);
    preconv<<<10240, 256, 0, stream>>>(Pre{W0, Ws, wf});

    PK pk{inputs, hidden, wf, fa, flags, out};
    void* args[] = {&pk};
    if (hipLaunchCooperativeKernel((void*)persist, dim3(256), dim3(512), args, 0, stream) != hipSuccess)
        persist<<<256, 512, 0, stream>>>(pk);
}

// Round 10
// 10217.923 us; speedup vs baseline: 2.5778x; 2.5778x over previous
//
#include <hip/hip_runtime.h>
#include <math.h>

// DARTS recurrent cell on MI355X — persistent cooperative kernel, v10.
// v9 reverted (global_load_lds lost L2 dedup: FETCH 75->211 MB/step).
// v10 = v7 structure with ONE variable changed: 8 waves -> 16 waves
// (1024-thread WGs), 2 ks/wave. Per-wave serial bytes halve, waves/CU
// double (8->16) -> ~2x memory-level parallelism per CU. W0h slab dropped
// (streams like other blocks) so LDS = 32KB arena only; VGPR must stay
// <=128 for 16 waves/CU.

typedef __attribute__((ext_vector_type(8))) _Float16 half8;
typedef __attribute__((ext_vector_type(4))) float f32x4;
typedef __attribute__((ext_vector_type(8))) unsigned short us8;

#define NH 1024
#define SCALE 2048.f
#define INVS  (1.f/2048.f)
#define WF_BYTES 83886080ull
#define FA_BYTES 1572864ull
#define T_STEPS  256

#define LBAR() asm volatile("s_waitcnt lgkmcnt(0)\n\ts_barrier" ::: "memory")

__device__ __forceinline__ float sigf(float x){ return 1.f/(1.f+__expf(-x)); }
__device__ __forceinline__ void limbs2(float x, _Float16& a, _Float16& b){
    a = (_Float16)x; b = (_Float16)((x - (float)a)*SCALE);
}

// ---------------- weight pre-swizzle (identical to v4-v9, proven) ------------
struct Pre { const float* W0; const float* Ws; unsigned short* wf; };

__global__ __launch_bounds__(256) void preconv(Pre d) {
    int gid  = blockIdx.x * 4 + (threadIdx.x >> 6);
    int lane = threadIdx.x & 63;
    const float* W; unsigned short* dst; int nks, cg, ks;
    if (gid < 8192) {
        W = d.W0; dst = d.wf; nks = 64; cg = gid >> 6; ks = gid & 63;
    } else {
        int g = gid - 8192; int mm = g >> 12; int wi = g & 4095;
        W   = d.Ws + (size_t)mm * (1024 * 2048);
        dst = d.wf + 8388608ull + (size_t)mm * 4194304ull;
        nks = 32; cg = wi >> 5; ks = wi & 31;
    }
    int c  = cg * 16 + (lane & 15);
    int kb = ks * 32 + (lane >> 4) * 8;
    half8 h0, h1;
    #pragma unroll
    for (int j = 0; j < 8; ++j) {
        _Float16 p, q; limbs2(W[(size_t)(kb + j) * 2048 + c], p, q);
        h0[j] = p; h1[j] = q;
    }
    unsigned short* o = dst + ((size_t)cg * nks + ks) * 1024 + lane * 8;
    *(half8*)o         = h0;
    *(half8*)(o + 512) = h1;
}

// -------- init: hidden -> interleaved H frag plane; flag init ----------------
__global__ __launch_bounds__(256) void initk(const float* hidden, char* fa, unsigned* flags) {
    int gid = blockIdx.x * 256 + threadIdx.x;
    if (gid < 1536) flags[gid] = (gid < 256) ? 1u : 0u;
    #pragma unroll
    for (int e = 0; e < 4; ++e) {
        int i = gid * 4 + e;
        int row = i >> 10, col = i & 1023;
        int rt = row >> 4, rowf = row & 15;
        int ksp = col >> 5, kin = col & 31;
        int lanep = (kin >> 3) * 16 + rowf;
        size_t off = (size_t)rt * 65536 + ((size_t)ksp * 64 + lanep) * 32 + (kin & 7) * 4;
        _Float16 u0, u1; limbs2(hidden[i], u0, u1);
        unsigned pk = (unsigned)__builtin_bit_cast(unsigned short, u0) |
                      ((unsigned)__builtin_bit_cast(unsigned short, u1) << 16);
        *(unsigned*)(fa + off) = pk;
    }
}

// ------------------------------ device helpers -------------------------------
__device__ __forceinline__ void aload(const char* fa, int ks, int lane, half8& a0, half8& a1) {
    const char* p = fa + ((size_t)ks * 64 + lane) * 32;
    us8 q0 = *(const us8*)p;
    us8 q1 = *(const us8*)(p + 16);
    a0 = __builtin_bit_cast(half8, __builtin_shufflevector(q0, q1, 0,2,4,6,8,10,12,14));
    a1 = __builtin_bit_cast(half8, __builtin_shufflevector(q0, q1, 1,3,5,7,9,11,13,15));
}
__device__ __forceinline__ half8 ldw(const unsigned short* p) { return *(const half8*)p; }
__device__ __forceinline__ void mfma6(half8 a0, half8 a1, half8 w0, half8 w1,
                                      f32x4& x0, f32x4& x1) {
    x0 = __builtin_amdgcn_mfma_f32_16x16x32_f16(a0, w0, x0, 0, 0, 0);
    x1 = __builtin_amdgcn_mfma_f32_16x16x32_f16(a0, w1, x1, 0, 0, 0);
    x1 = __builtin_amdgcn_mfma_f32_16x16x32_f16(a1, w0, x1, 0, 0, 0);
}
__device__ __forceinline__ void rwrite1(float* arena, int wave, int lane,
        f32x4 c0, f32x4 c1, f32x4 h0, f32x4 h1) {
    float* b = arena + wave * 512;
    #pragma unroll
    for (int r = 0; r < 4; ++r) {
        b[lane * 4 + r]       = c0[r] + c1[r] * INVS;
        b[256 + lane * 4 + r] = h0[r] + h1[r] * INVS;
    }
}
__device__ __forceinline__ void rsum1(const float* arena, int idx, float& cs, float& hs) {
    float c = 0.f, h = 0.f;
    #pragma unroll
    for (int w = 0; w < 16; ++w) {
        c += arena[w * 512 + idx];
        h += arena[w * 512 + 256 + idx];
    }
    cs = c; hs = h;
}
__device__ __forceinline__ void fstore(char* fa, int offp, float v) {
    _Float16 u0, u1; limbs2(v, u0, u1);
    unsigned pk = (unsigned)__builtin_bit_cast(unsigned short, u0) |
                  ((unsigned)__builtin_bit_cast(unsigned short, u1) << 16);
    __hip_atomic_store((unsigned*)(fa + offp), pk, __ATOMIC_RELAXED, __HIP_MEMORY_SCOPE_AGENT);
}
template<int ACQ>
__device__ __forceinline__ void pollw(unsigned* f, unsigned tgt, int lane) {
    unsigned v = __hip_atomic_load(f + lane, __ATOMIC_RELAXED, __HIP_MEMORY_SCOPE_AGENT);
    while (__ballot(v < tgt)) {
        __builtin_amdgcn_s_sleep(2);
        v = __hip_atomic_load(f + lane, __ATOMIC_RELAXED, __HIP_MEMORY_SCOPE_AGENT);
    }
    if (ACQ)
        (void)__hip_atomic_load(f, __ATOMIC_ACQUIRE, __HIP_MEMORY_SCOPE_AGENT);
}
__device__ __forceinline__ void publish(unsigned* slot, unsigned v) {
    __hip_atomic_store(slot, v, __ATOMIC_RELAXED, __HIP_MEMORY_SCOPE_AGENT);
}

// ------------------------------ persistent kernel ----------------------------
struct PK {
    const float* x; const float* hidden;
    const unsigned short* wf;
    char* fa; unsigned* flags; float* out;
};

__global__ __launch_bounds__(1024) void persist(PK p) {
    __shared__ float arena[16 * 512];        // 32 KB reduce arena (16 waves)

    const int tid = threadIdx.x;
    const int wave = tid >> 6, lane = tid & 63;   // wave 0..15
    const int l15 = lane & 15, lg = lane >> 4;
    const int lane8 = lane * 8, lg8 = lg * 8;
    const int bx = blockIdx.x;
    const int cg = (bx & 7) * 8 + ((bx >> 3) & 7);   // same cg set -> same XCD
    const int rt = bx >> 6;

    const unsigned short* wf0 = p.wf;
    const unsigned short* wfs[8];
    #pragma unroll
    for (int i = 0; i < 8; ++i) wfs[i] = p.wf + 8388608ull + (size_t)i * 4194304ull;

    char* FAH  = p.fa + (size_t)(0 * 4 + rt) * 65536;
    char* FAS0 = p.fa + (size_t)(1 * 4 + rt) * 65536;
    char* FAS1 = p.fa + (size_t)(2 * 4 + rt) * 65536;
    char* FAS2 = p.fa + (size_t)(3 * 4 + rt) * 65536;
    char* FAS3 = p.fa + (size_t)(4 * 4 + rt) * 65536;
    char* FAS5 = p.fa + (size_t)(5 * 4 + rt) * 65536;
    #define FLG(tn) (p.flags + ((tn) * 4 + rt) * 64)

    // load this wave's 2-ks weight frags of one matrix (c+h col blocks)
    #define WLOAD(wbuf, wfp, nks, kbase) do { \
        _Pragma("unroll") \
        for (int _i = 0; _i < 2; ++_i) { \
            const int _ks = (kbase) + wave * 2 + _i; \
            const unsigned short* _pc = (wfp) + ((size_t)cg * (nks) + _ks) * 1024 + lane8; \
            const unsigned short* _ph = (wfp) + ((size_t)(cg + 64) * (nks) + _ks) * 1024 + lane8; \
            wbuf[_i][0] = ldw(_pc); wbuf[_i][1] = ldw(_pc + 512); \
            wbuf[_i][2] = ldw(_ph); wbuf[_i][3] = ldw(_ph + 512); } } while (0)
    #define ALD(dst0, dst1, fa) do { \
        _Pragma("unroll") \
        for (int _i = 0; _i < 2; ++_i) aload(fa, wave * 2 + _i, lane, dst0[_i], dst1[_i]); } while (0)
    #define GEMM(wbuf, A0, A1, X0, X1, Y0, Y1) do { \
        _Pragma("unroll") \
        for (int _i = 0; _i < 2; ++_i) { \
            mfma6(A0[_i], A1[_i], wbuf[_i][0], wbuf[_i][1], X0, X1); \
            mfma6(A0[_i], A1[_i], wbuf[_i][2], wbuf[_i][3], Y0, Y1); } } while (0)

    const int rowf = tid >> 4, colf = tid & 15;            // epilogue pos (tid<256)
    const size_t opos = (size_t)(rt * 16 + rowf) * NH + cg * 16 + colf;
    const int idx = colf * 4 + (rowf >> 2) * 64 + (rowf & 3);
    int offp;
    {
        int col = cg * 16 + colf;
        int ksp = col >> 5, kin = col & 31;
        int lanep = (kin >> 3) * 16 + rowf;
        offp = (ksp * 64 + lanep) * 32 + (kin & 7) * 4;
    }
    float hprev = 0.f, s0v = 0.f, s1v = 0.f, s2v = 0.f, s3v = 0.f, s5v = 0.f, runsum = 0.f;
    if (tid < 256) hprev = p.hidden[opos];
    const int xrow = rt * 16 + l15;
    __syncthreads();

    for (int t = 0; t < T_STEPS; ++t) {
        const float* xt = p.x + (size_t)t * 65536;
        half8 a0[2], a1[2];

        // ===== L1: x-part pre-poll (h-independent); h-part post-acquire ======
        f32x4 c0 = {}, c1 = {}, h0 = {}, h1 = {};
        {
            half8 wx[2][4], xa0[2], xa1[2];
            WLOAD(wx, wf0, 64, 0);                       // W0 x-rows
            #pragma unroll
            for (int i = 0; i < 2; ++i) {
                const int ks = wave * 2 + i;
                const float* xp = xt + (size_t)xrow * NH + ks * 32 + lg8;
                float4 v0 = *(const float4*)xp, v1 = *(const float4*)(xp + 4);
                float fv[8] = {v0.x, v0.y, v0.z, v0.w, v1.x, v1.y, v1.z, v1.w};
                #pragma unroll
                for (int j = 0; j < 8; ++j) { _Float16 u, w2; limbs2(fv[j], u, w2); xa0[i][j] = u; xa1[i][j] = w2; }
            }
            GEMM(wx, xa0, xa1, c0, c1, h0, h1);
            half8 wh[2][4];
            WLOAD(wh, wf0, 64, 32);                      // W0 h-rows (pre-poll issue)
            if (wave == 15) pollw<1>(FLG(0), t + 1, lane);   // the step's ONE acquire
            __syncthreads();
            half8 ha0[2], ha1[2];
            ALD(ha0, ha1, FAH);
            GEMM(wh, ha0, ha1, c0, c1, h0, h1);
            rwrite1(arena, wave, lane, c0, c1, h0, h1);
        }
        LBAR();
        if (tid < 256) {
            float cs, hs; rsum1(arena, idx, cs, hs);
            s0v = hprev + sigf(cs) * (tanhf(hs) - hprev);
            fstore(FAS0, offp, s0v);
        }
        __syncthreads();
        if (tid == 0) publish(FLG(1) + cg, t + 1);

        // ===== L2: s1 = comb(s0, s0 @ Ws0) ===================================
        {
            half8 w0[2][4];
            WLOAD(w0, wfs[0], 32, 0);
            if (wave == 15) pollw<0>(FLG(1), t + 1, lane);
            __syncthreads();
            ALD(a0, a1, FAS0);
            f32x4 X0 = {}, X1 = {}, Y0 = {}, Y1 = {};
            GEMM(w0, a0, a1, X0, X1, Y0, Y1);
            rwrite1(arena, wave, lane, X0, X1, Y0, Y1);
        }
        LBAR();
        if (tid < 256) {
            float cs, hs; rsum1(arena, idx, cs, hs);
            s1v = s0v + sigf(cs) * (sigf(hs) - s0v);
            fstore(FAS1, offp, s1v);
            runsum = s1v;
        }
        __syncthreads();
        if (tid == 0) publish(FLG(2) + cg, t + 1);

        // ===== L3: s2,s3,s4 from s1 (Ws1,Ws2,Ws3) ============================
        {
            half8 w1[2][4], w2[2][4];
            WLOAD(w1, wfs[1], 32, 0);
            WLOAD(w2, wfs[2], 32, 0);
            if (wave == 15) pollw<0>(FLG(2), t + 1, lane);
            __syncthreads();
            ALD(a0, a1, FAS1);
            f32x4 X0 = {}, X1 = {}, Y0 = {}, Y1 = {};
            GEMM(w1, a0, a1, X0, X1, Y0, Y1);
            half8 w3[2][4];
            WLOAD(w3, wfs[3], 32, 0);
            rwrite1(arena, wave, lane, X0, X1, Y0, Y1);
            LBAR();
            if (tid < 256) {
                float cs, hs; rsum1(arena, idx, cs, hs);
                s2v = s1v + sigf(cs) * (fmaxf(hs, 0.f) - s1v);
                fstore(FAS2, offp, s2v);
            }
            __syncthreads();
            if (tid == 0) publish(FLG(3) + cg, t + 1);
            X0 = (f32x4){}; X1 = (f32x4){}; Y0 = (f32x4){}; Y1 = (f32x4){};
            GEMM(w2, a0, a1, X0, X1, Y0, Y1);
            rwrite1(arena, wave, lane, X0, X1, Y0, Y1);
            LBAR();
            if (tid < 256) {
                float cs, hs; rsum1(arena, idx, cs, hs);
                s3v = s1v + sigf(cs) * (fmaxf(hs, 0.f) - s1v);
                fstore(FAS3, offp, s3v);
            }
            __syncthreads();
            if (tid == 0) publish(FLG(4) + cg, t + 1);
            X0 = (f32x4){}; X1 = (f32x4){}; Y0 = (f32x4){}; Y1 = (f32x4){};
            GEMM(w3, a0, a1, X0, X1, Y0, Y1);
            rwrite1(arena, wave, lane, X0, X1, Y0, Y1);
            LBAR();
            if (tid < 256) {
                float cs, hs; rsum1(arena, idx, cs, hs);
                float s4v = s1v + sigf(cs) * (hs - s1v);
                runsum += s2v + s3v + s4v;
            }
        }
        // no barrier: L4's post-poll sync orders arena reuse

        // ===== L4: s5 = comb(s2,Ws4), s7 = comb(s3,Ws6) ======================
        {
            half8 w4[2][4], w6[2][4];
            WLOAD(w4, wfs[4], 32, 0);
            WLOAD(w6, wfs[6], 32, 0);
            if (wave == 15) { pollw<0>(FLG(3), t + 1, lane); pollw<0>(FLG(4), t + 1, lane); }
            __syncthreads();
            half8 b0[2], b1[2];
            ALD(a0, a1, FAS2);
            ALD(b0, b1, FAS3);
            f32x4 X0 = {}, X1 = {}, Y0 = {}, Y1 = {};
            GEMM(w4, a0, a1, X0, X1, Y0, Y1);
            f32x4 U0 = {}, U1 = {}, V0 = {}, V1 = {};
            GEMM(w6, b0, b1, U0, U1, V0, V1);
            rwrite1(arena, wave, lane, X0, X1, Y0, Y1);
            LBAR();
            if (tid < 256) {
                float cs, hs; rsum1(arena, idx, cs, hs);
                s5v = s2v + sigf(cs) * (tanhf(hs) - s2v);
                fstore(FAS5, offp, s5v);
            }
            __syncthreads();
            if (tid == 0) publish(FLG(5) + cg, t + 1);
            rwrite1(arena, wave, lane, U0, U1, V0, V1);
            LBAR();
            if (tid < 256) {
                float cs, hs; rsum1(arena, idx, cs, hs);
                float s7v = s3v + sigf(cs) * (tanhf(hs) - s3v);
                runsum += s5v + s7v;
            }
        }
        // no barrier: L5's post-poll sync orders arena reuse

        // ===== L5: s6,s8 from s5 + mean -> out[t], publish H =================
        {
            half8 w5[2][4], w7[2][4];
            WLOAD(w5, wfs[5], 32, 0);
            WLOAD(w7, wfs[7], 32, 0);
            if (wave == 15) pollw<0>(FLG(5), t + 1, lane);
            __syncthreads();
            ALD(a0, a1, FAS5);
            f32x4 X0 = {}, X1 = {}, Y0 = {}, Y1 = {};
            GEMM(w5, a0, a1, X0, X1, Y0, Y1);
            f32x4 U0 = {}, U1 = {}, V0 = {}, V1 = {};
            GEMM(w7, a0, a1, U0, U1, V0, V1);
            rwrite1(arena, wave, lane, X0, X1, Y0, Y1);
            LBAR();
            float c6 = 0.f, h6 = 0.f;
            if (tid < 256) rsum1(arena, idx, c6, h6);
            LBAR();                                      // readers done before rewrite
            rwrite1(arena, wave, lane, U0, U1, V0, V1);
            LBAR();
            if (tid < 256) {
                float c8, h8; rsum1(arena, idx, c8, h8);
                float s6 = s5v + sigf(c6) * (sigf(h6) - s5v);
                float s8 = s5v + sigf(c8) * (fmaxf(h8, 0.f) - s5v);
                float v = 0.125f * (runsum + s6 + s8);
                p.out[(size_t)t * 65536 + opos] = v;
                fstore(FAH, offp, v);
                hprev = v;
            }
            __syncthreads();
            if (tid == 0) publish(FLG(0) + cg, t + 2);
        }
    }
    #undef FLG
    #undef WLOAD
    #undef ALD
    #undef GEMM
}

// ---------------------------------- host -------------------------------------
extern "C" void kernel_launch(void* const* d_in, const int* in_sizes, int n_in,
                              void* d_out, int out_size, void* d_ws, size_t ws_size,
                              hipStream_t stream) {
    (void)in_sizes; (void)n_in; (void)out_size; (void)ws_size;
    const float* inputs = (const float*)d_in[0];
    const float* hidden = (const float*)d_in[1];
    const float* W0     = (const float*)d_in[2];
    const float* Ws     = (const float*)d_in[3];
    float* out = (float*)d_out;

    char* base = (char*)d_ws;
    unsigned short* wf = (unsigned short*)base;
    char* fa = base + WF_BYTES;
    unsigned* flags = (unsigned*)(fa + FA_BYTES);

    initk<<<64, 256, 0, stream>>>(hidden, fa, flags);
    preconv<<<10240, 256, 0, stream>>>(Pre{W0, Ws, wf});

    PK pk{inputs, hidden, wf, fa, flags, out};
    void* args[] = {&pk};
    if (hipLaunchCooperativeKernel((void*)persist, dim3(256), dim3(1024), args, 0, stream) != hipSuccess)
        persist<<<256, 1024, 0, stream>>>(pk);
}